// Round 2
// baseline (1019.700 us; speedup 1.0000x reference)
//
#include <hip/hip_runtime.h>
#include <hip/hip_bf16.h>

#define N_NODES 100000
#define N_EDGES 800000
#define D 128
#define NH 8
#define DH 16

typedef __hip_bfloat16 bf16;

// 8 packed bf16 (one uint4) -> 8 f32
__device__ __forceinline__ void b8_to_f32(uint4 u, float* out8) {
    unsigned v[4] = {u.x, u.y, u.z, u.w};
#pragma unroll
    for (int k = 0; k < 4; ++k) {
        out8[2 * k]     = __uint_as_float(v[k] << 16);
        out8[2 * k + 1] = __uint_as_float(v[k] & 0xffff0000u);
    }
}

__device__ __forceinline__ unsigned short f2bu(float x) {
    bf16 b = __float2bfloat16(x);
    return *reinterpret_cast<unsigned short*>(&b);
}

// ---------------------------------------------------------------------------
// Kernel 1: Q/K/V projection.  O = E @ W  (E: [N,128] f32, W: [128,128] f32,
// O: [N,128] bf16).  Block tile 64 rows x 64 cols, 4x4 register tile.
// grid = (ceil(N/64), 2, 3); z picks which weight/output.
// ---------------------------------------------------------------------------
__global__ __launch_bounds__(256) void qkv_gemm(
    const float* __restrict__ E,
    const float* __restrict__ Wq, const float* __restrict__ Wk, const float* __restrict__ Wv,
    bf16* __restrict__ Q, bf16* __restrict__ K, bf16* __restrict__ V)
{
    const float* W = (blockIdx.z == 0) ? Wq : (blockIdx.z == 1) ? Wk : Wv;
    bf16* O        = (blockIdx.z == 0) ? Q  : (blockIdx.z == 1) ? K  : V;

    const int row0 = blockIdx.x * 64;
    const int col0 = blockIdx.y * 64;
    const int t = threadIdx.x;

    __shared__ float As[64][132];   // +4 pad: float4-aligned rows, spreads banks
    __shared__ float Bs[128][64];

    // Stage A tile: 64 rows x 128 k = 2048 float4s; 8 float4 per thread.
#pragma unroll
    for (int it = 0; it < 8; ++it) {
        int i  = it * 256 + t;      // float4 index
        int r  = i >> 5;            // 32 float4 per row
        int c4 = i & 31;
        int gr = row0 + r;
        float4 a = (gr < N_NODES)
            ? *reinterpret_cast<const float4*>(E + (size_t)gr * D + c4 * 4)
            : make_float4(0.f, 0.f, 0.f, 0.f);
        *reinterpret_cast<float4*>(&As[r][c4 * 4]) = a;
    }
    // Stage B tile: 128 k x 64 cols = 2048 float4s.
#pragma unroll
    for (int it = 0; it < 8; ++it) {
        int i  = it * 256 + t;
        int d  = i >> 4;            // 16 float4 per row of the 64-wide tile
        int j4 = i & 15;
        float4 b = *reinterpret_cast<const float4*>(W + (size_t)d * D + col0 + j4 * 4);
        *reinterpret_cast<float4*>(&Bs[d][j4 * 4]) = b;
    }
    __syncthreads();

    const int tx = t & 15;   // col group: cols tx*4..tx*4+3
    const int ty = t >> 4;   // row group: rows ty*4..ty*4+3

    float acc[4][4] = {};
#pragma unroll 8
    for (int d4 = 0; d4 < 32; ++d4) {
        float4 a[4], b[4];
#pragma unroll
        for (int i = 0; i < 4; ++i)
            a[i] = *reinterpret_cast<const float4*>(&As[ty * 4 + i][d4 * 4]);
#pragma unroll
        for (int k = 0; k < 4; ++k)
            b[k] = *reinterpret_cast<const float4*>(&Bs[d4 * 4 + k][tx * 4]);
#pragma unroll
        for (int i = 0; i < 4; ++i) {
            float4 ai = a[i];
            acc[i][0] += ai.x * b[0].x + ai.y * b[1].x + ai.z * b[2].x + ai.w * b[3].x;
            acc[i][1] += ai.x * b[0].y + ai.y * b[1].y + ai.z * b[2].y + ai.w * b[3].y;
            acc[i][2] += ai.x * b[0].z + ai.y * b[1].z + ai.z * b[2].z + ai.w * b[3].z;
            acc[i][3] += ai.x * b[0].w + ai.y * b[1].w + ai.z * b[2].w + ai.w * b[3].w;
        }
    }

#pragma unroll
    for (int i = 0; i < 4; ++i) {
        int row = row0 + ty * 4 + i;
        if (row < N_NODES) {
            ushort4 o;
            o.x = f2bu(acc[i][0]); o.y = f2bu(acc[i][1]);
            o.z = f2bu(acc[i][2]); o.w = f2bu(acc[i][3]);
            *reinterpret_cast<ushort4*>(O + (size_t)row * D + col0 + tx * 4) = o;
        }
    }
}

// ---------------------------------------------------------------------------
// Kernel 2: per-(edge,head) attention score. s = exp(clip(q.k)); atomic norm.
// ---------------------------------------------------------------------------
__global__ __launch_bounds__(256) void edge_att(
    const bf16* __restrict__ Q, const bf16* __restrict__ K,
    const int* __restrict__ rows, const int* __restrict__ cols,
    float* __restrict__ S, float* __restrict__ norm)
{
    int t = blockIdx.x * 256 + threadIdx.x;   // over E*NH = 6.4M
    int e = t >> 3;
    int h = t & 7;
    int r = rows[e];
    int c = cols[e];
    const uint4* qp = reinterpret_cast<const uint4*>(Q + (size_t)r * D + h * DH);
    const uint4* kp = reinterpret_cast<const uint4*>(K + (size_t)c * D + h * DH);
    float qf[16], kf[16];
    b8_to_f32(qp[0], qf);
    b8_to_f32(qp[1], qf + 8);
    b8_to_f32(kp[0], kf);
    b8_to_f32(kp[1], kf + 8);
    float s = 0.0f;
#pragma unroll
    for (int i = 0; i < 16; ++i) s += qf[i] * kf[i];
    s = fminf(fmaxf(s, -10.0f), 10.0f);
    s = __expf(s);
    S[t] = s;
    atomicAdd(&norm[r * NH + h], s);
}

// ---------------------------------------------------------------------------
// Kernel 3: norm -> 1/(norm + 1e-8) in place.
// ---------------------------------------------------------------------------
__global__ __launch_bounds__(256) void rnorm_kernel(float* __restrict__ norm)
{
    int t = blockIdx.x * 256 + threadIdx.x;   // over N*NH = 800000
    if (t < N_NODES * NH) norm[t] = 1.0f / (norm[t] + 1e-8f);
}

// ---------------------------------------------------------------------------
// Kernel 4: per-(edge, dim-pair) weighted aggregation via f32 atomics into out.
// ---------------------------------------------------------------------------
__global__ __launch_bounds__(256) void edge_agg(
    const bf16* __restrict__ V,
    const int* __restrict__ rows, const int* __restrict__ cols,
    const float* __restrict__ S, const float* __restrict__ rn,
    float* __restrict__ out)
{
    int t = blockIdx.x * 256 + threadIdx.x;   // over E*64 = 51.2M
    int e  = t >> 6;
    int dp = t & 63;            // dim pair: dims 2dp, 2dp+1
    int h  = dp >> 3;
    int r = rows[e];
    int c = cols[e];
    float w = S[e * NH + h] * rn[r * NH + h];
    unsigned v2 = *reinterpret_cast<const unsigned*>(V + (size_t)c * D + dp * 2);
    float v0 = __uint_as_float(v2 << 16);
    float v1 = __uint_as_float(v2 & 0xffff0000u);
    atomicAdd(&out[(size_t)r * D + dp * 2],     w * v0);
    atomicAdd(&out[(size_t)r * D + dp * 2 + 1], w * v1);
}

// ---------------------------------------------------------------------------
// Kernel 5: residual + LayerNorm, f32, in place on out. One wave per node.
// Each thread reads only elements it later writes -> in-place safe.
// ---------------------------------------------------------------------------
__global__ __launch_bounds__(256) void ln_kernel(
    float* __restrict__ out, const float* __restrict__ emb,
    const float* __restrict__ gamma, const float* __restrict__ beta)
{
    int n = blockIdx.x * 4 + (threadIdx.x >> 6);
    int lane = threadIdx.x & 63;
    if (n >= N_NODES) return;
    size_t base = (size_t)n * D;
    float x0 = out[base + lane]      + emb[base + lane];
    float x1 = out[base + 64 + lane] + emb[base + 64 + lane];

    float s = x0 + x1;
#pragma unroll
    for (int off = 32; off; off >>= 1) s += __shfl_xor(s, off, 64);
    float mean = s * (1.0f / 128.0f);

    float d0 = x0 - mean, d1 = x1 - mean;
    float v = d0 * d0 + d1 * d1;
#pragma unroll
    for (int off = 32; off; off >>= 1) v += __shfl_xor(v, off, 64);
    float rs = rsqrtf(v * (1.0f / 128.0f) + 1e-6f);

    out[base + lane]      = d0 * rs * gamma[lane]      + beta[lane];
    out[base + 64 + lane] = d1 * rs * gamma[64 + lane] + beta[64 + lane];
}

// ---------------------------------------------------------------------------
extern "C" void kernel_launch(void* const* d_in, const int* in_sizes, int n_in,
                              void* d_out, int out_size, void* d_ws, size_t ws_size,
                              hipStream_t stream)
{
    const float* emb   = (const float*)d_in[0];
    const float* qW    = (const float*)d_in[1];
    const float* kW    = (const float*)d_in[2];
    const float* vW    = (const float*)d_in[3];
    const float* gamma = (const float*)d_in[4];
    const float* beta  = (const float*)d_in[5];
    const int*   eidx  = (const int*)d_in[6];
    const int*   rows  = eidx;              // destination / segment indices
    const int*   cols  = eidx + N_EDGES;    // source indices
    float* out = (float*)d_out;

    // Workspace layout: Qb,Kb,Vb bf16 [N*D each], then f32 S [E*NH], norm [N*NH]
    // Total: 3*25.6MB + 25.6MB + 3.2MB = 105.6MB
    bf16* Qb = (bf16*)d_ws;
    bf16* Kb = Qb + (size_t)N_NODES * D;
    bf16* Vb = Kb + (size_t)N_NODES * D;
    float* S    = (float*)(Vb + (size_t)N_NODES * D);
    float* norm = S + (size_t)N_EDGES * NH;

    // Zero the norm accumulator and the output accumulator (res lives in out).
    hipMemsetAsync(norm, 0, (size_t)N_NODES * NH * sizeof(float), stream);
    hipMemsetAsync(out, 0, (size_t)N_NODES * D * sizeof(float), stream);

    dim3 g1((N_NODES + 63) / 64, 2, 3);
    qkv_gemm<<<g1, 256, 0, stream>>>(emb, qW, kW, vW, Qb, Kb, Vb);

    edge_att<<<(N_EDGES * NH) / 256, 256, 0, stream>>>(Qb, Kb, rows, cols, S, norm);

    rnorm_kernel<<<(N_NODES * NH + 255) / 256, 256, 0, stream>>>(norm);

    edge_agg<<<(int)(((size_t)N_EDGES * 64) / 256), 256, 0, stream>>>(Vb, rows, cols, S, norm, out);

    ln_kernel<<<(N_NODES + 3) / 4, 256, 0, stream>>>(out, emb, gamma, beta);
}

// Round 3
// 439.525 us; speedup vs baseline: 2.3200x; 2.3200x over previous
//
#include <hip/hip_runtime.h>
#include <hip/hip_bf16.h>

#define N_NODES 100000
#define N_EDGES 800000
#define D 128
#define NH 8
#define DH 16
#define NB ((N_NODES + 255) / 256)   // 391 scan blocks

typedef __hip_bfloat16 bf16;

__device__ __forceinline__ unsigned short f2bu(float x) {
    bf16 b = __float2bfloat16(x);
    return *reinterpret_cast<unsigned short*>(&b);
}

// ---------------------------------------------------------------------------
// Kernel 1: Q/K/V projection.  O = E @ W  (E: [N,128] f32, W: [128,128] f32,
// O: [N,128] bf16).  Block tile 64 rows x 64 cols, 4x4 register tile.
// grid = (ceil(N/64), 2, 3); z picks which weight/output.  (known-good)
// ---------------------------------------------------------------------------
__global__ __launch_bounds__(256) void qkv_gemm(
    const float* __restrict__ E,
    const float* __restrict__ Wq, const float* __restrict__ Wk, const float* __restrict__ Wv,
    bf16* __restrict__ Q, bf16* __restrict__ K, bf16* __restrict__ V)
{
    const float* W = (blockIdx.z == 0) ? Wq : (blockIdx.z == 1) ? Wk : Wv;
    bf16* O        = (blockIdx.z == 0) ? Q  : (blockIdx.z == 1) ? K  : V;

    const int row0 = blockIdx.x * 64;
    const int col0 = blockIdx.y * 64;
    const int t = threadIdx.x;

    __shared__ float As[64][132];
    __shared__ float Bs[128][64];

#pragma unroll
    for (int it = 0; it < 8; ++it) {
        int i  = it * 256 + t;
        int r  = i >> 5;
        int c4 = i & 31;
        int gr = row0 + r;
        float4 a = (gr < N_NODES)
            ? *reinterpret_cast<const float4*>(E + (size_t)gr * D + c4 * 4)
            : make_float4(0.f, 0.f, 0.f, 0.f);
        *reinterpret_cast<float4*>(&As[r][c4 * 4]) = a;
    }
#pragma unroll
    for (int it = 0; it < 8; ++it) {
        int i  = it * 256 + t;
        int d  = i >> 4;
        int j4 = i & 15;
        float4 b = *reinterpret_cast<const float4*>(W + (size_t)d * D + col0 + j4 * 4);
        *reinterpret_cast<float4*>(&Bs[d][j4 * 4]) = b;
    }
    __syncthreads();

    const int tx = t & 15;
    const int ty = t >> 4;

    float acc[4][4] = {};
#pragma unroll 8
    for (int d4 = 0; d4 < 32; ++d4) {
        float4 a[4], b[4];
#pragma unroll
        for (int i = 0; i < 4; ++i)
            a[i] = *reinterpret_cast<const float4*>(&As[ty * 4 + i][d4 * 4]);
#pragma unroll
        for (int k = 0; k < 4; ++k)
            b[k] = *reinterpret_cast<const float4*>(&Bs[d4 * 4 + k][tx * 4]);
#pragma unroll
        for (int i = 0; i < 4; ++i) {
            float4 ai = a[i];
            acc[i][0] += ai.x * b[0].x + ai.y * b[1].x + ai.z * b[2].x + ai.w * b[3].x;
            acc[i][1] += ai.x * b[0].y + ai.y * b[1].y + ai.z * b[2].y + ai.w * b[3].y;
            acc[i][2] += ai.x * b[0].z + ai.y * b[1].z + ai.z * b[2].z + ai.w * b[3].z;
            acc[i][3] += ai.x * b[0].w + ai.y * b[1].w + ai.z * b[2].w + ai.w * b[3].w;
        }
    }

#pragma unroll
    for (int i = 0; i < 4; ++i) {
        int row = row0 + ty * 4 + i;
        if (row < N_NODES) {
            ushort4 o;
            o.x = f2bu(acc[i][0]); o.y = f2bu(acc[i][1]);
            o.z = f2bu(acc[i][2]); o.w = f2bu(acc[i][3]);
            *reinterpret_cast<ushort4*>(O + (size_t)row * D + col0 + tx * 4) = o;
        }
    }
}

// ---------------------------------------------------------------------------
// CSR build: histogram -> 3-kernel exclusive scan -> scatter
// ---------------------------------------------------------------------------
__global__ __launch_bounds__(256) void hist_kernel(
    const int* __restrict__ rows, int* __restrict__ counts)
{
    int e = blockIdx.x * 256 + threadIdx.x;
    if (e < N_EDGES) atomicAdd(&counts[rows[e]], 1);
}

// Per-block inclusive scan of 256 counts -> exclusive partial + block total.
__global__ __launch_bounds__(256) void scan_block(
    const int* __restrict__ counts, int* __restrict__ scanned, int* __restrict__ block_sums)
{
    __shared__ int s[256];
    int tid = threadIdx.x;
    int i = blockIdx.x * 256 + tid;
    int v = (i < N_NODES) ? counts[i] : 0;
    s[tid] = v;
    __syncthreads();
#pragma unroll
    for (int off = 1; off < 256; off <<= 1) {
        int t = (tid >= off) ? s[tid - off] : 0;
        __syncthreads();
        s[tid] += t;
        __syncthreads();
    }
    if (i < N_NODES) scanned[i] = s[tid] - v;   // exclusive
    if (tid == 255) block_sums[blockIdx.x] = s[255];
}

// Single-block exclusive scan of the NB block totals (NB=391 <= 512).
__global__ __launch_bounds__(512) void scan_tops(int* __restrict__ block_sums)
{
    __shared__ int s[512];
    int tid = threadIdx.x;
    int v = (tid < NB) ? block_sums[tid] : 0;
    s[tid] = v;
    __syncthreads();
#pragma unroll
    for (int off = 1; off < 512; off <<= 1) {
        int t = (tid >= off) ? s[tid - off] : 0;
        __syncthreads();
        s[tid] += t;
        __syncthreads();
    }
    if (tid < NB) block_sums[tid] = s[tid] - v;  // exclusive
}

// Add block offsets; produce final offsets and a scatter cursor copy.
__global__ __launch_bounds__(256) void scan_add(
    int* __restrict__ scanned, const int* __restrict__ block_sums, int* __restrict__ cursor)
{
    int i = blockIdx.x * 256 + threadIdx.x;
    if (i < N_NODES) {
        int o = scanned[i] + block_sums[blockIdx.x];
        scanned[i] = o;       // now the true exclusive offsets
        cursor[i]  = o;
    }
}

__global__ __launch_bounds__(256) void scatter_kernel(
    const int* __restrict__ rows, const int* __restrict__ cols,
    int* __restrict__ cursor, int* __restrict__ csr_cols)
{
    int e = blockIdx.x * 256 + threadIdx.x;
    if (e < N_EDGES) {
        int pos = atomicAdd(&cursor[rows[e]], 1);
        csr_cols[pos] = cols[e];
    }
}

// ---------------------------------------------------------------------------
// Fused per-node attention + residual + LayerNorm.  One wave per node.
// Lane l holds dims {2l, 2l+1}; head h = lanes 8h..8h+7.
// ---------------------------------------------------------------------------
__global__ __launch_bounds__(256) void fused_node(
    const bf16* __restrict__ Qb, const bf16* __restrict__ Kb, const bf16* __restrict__ Vb,
    const int* __restrict__ offsets, const int* __restrict__ counts,
    const int* __restrict__ csr_cols,
    const float* __restrict__ emb,
    const float* __restrict__ gamma, const float* __restrict__ beta,
    float* __restrict__ out)
{
    int n = blockIdx.x * 4 + (threadIdx.x >> 6);
    int lane = threadIdx.x & 63;
    if (n >= N_NODES) return;

    unsigned qu = *reinterpret_cast<const unsigned*>(Qb + (size_t)n * D + lane * 2);
    float q0 = __uint_as_float(qu << 16);
    float q1 = __uint_as_float(qu & 0xffff0000u);

    int start = offsets[n];
    int cnt   = counts[n];

    float acc0 = 0.f, acc1 = 0.f, nrm = 0.f;
    for (int base = 0; base < cnt; base += 64) {
        int m = cnt - base; if (m > 64) m = 64;
        int myc = (base + lane < cnt) ? csr_cols[start + base + lane] : 0;
        for (int j = 0; j < m; ++j) {
            int c = __shfl(myc, j, 64);
            unsigned ku = *reinterpret_cast<const unsigned*>(Kb + (size_t)c * D + lane * 2);
            unsigned vu = *reinterpret_cast<const unsigned*>(Vb + (size_t)c * D + lane * 2);
            float k0 = __uint_as_float(ku << 16);
            float k1 = __uint_as_float(ku & 0xffff0000u);
            float p = q0 * k0 + q1 * k1;
            p += __shfl_xor(p, 1, 64);   // reduce within the 8-lane head group
            p += __shfl_xor(p, 2, 64);
            p += __shfl_xor(p, 4, 64);
            float s = __expf(fminf(fmaxf(p, -10.f), 10.f));
            nrm  += s;                   // per-lane copy of its head's norm
            acc0 += s * __uint_as_float(vu << 16);
            acc1 += s * __uint_as_float(vu & 0xffff0000u);
        }
    }

    float w = 1.f / (nrm + 1e-8f);
    float2 e2 = *reinterpret_cast<const float2*>(emb + (size_t)n * D + lane * 2);
    float x0 = acc0 * w + e2.x;
    float x1 = acc1 * w + e2.y;

    float ssum = x0 + x1;
#pragma unroll
    for (int off = 32; off; off >>= 1) ssum += __shfl_xor(ssum, off, 64);
    float mean = ssum * (1.0f / 128.0f);
    float d0 = x0 - mean, d1 = x1 - mean;
    float var = d0 * d0 + d1 * d1;
#pragma unroll
    for (int off = 32; off; off >>= 1) var += __shfl_xor(var, off, 64);
    float rs = rsqrtf(var * (1.0f / 128.0f) + 1e-6f);

    float2 g2 = *reinterpret_cast<const float2*>(gamma + lane * 2);
    float2 b2 = *reinterpret_cast<const float2*>(beta + lane * 2);
    float2 o2 = make_float2(d0 * rs * g2.x + b2.x, d1 * rs * g2.y + b2.y);
    *reinterpret_cast<float2*>(out + (size_t)n * D + lane * 2) = o2;
}

// ---------------------------------------------------------------------------
extern "C" void kernel_launch(void* const* d_in, const int* in_sizes, int n_in,
                              void* d_out, int out_size, void* d_ws, size_t ws_size,
                              hipStream_t stream)
{
    const float* emb   = (const float*)d_in[0];
    const float* qW    = (const float*)d_in[1];
    const float* kW    = (const float*)d_in[2];
    const float* vW    = (const float*)d_in[3];
    const float* gamma = (const float*)d_in[4];
    const float* beta  = (const float*)d_in[5];
    const int*   eidx  = (const int*)d_in[6];
    const int*   rows  = eidx;              // destination / segment indices
    const int*   cols  = eidx + N_EDGES;    // source indices
    float* out = (float*)d_out;

    // Workspace: Qb,Kb,Vb bf16 [N*D each] (76.8MB), then int arrays (~4.5MB)
    const size_t ND = (size_t)N_NODES * D;
    bf16* Qb = (bf16*)d_ws;
    bf16* Kb = Qb + ND;
    bf16* Vb = Kb + ND;
    int* counts     = (int*)(Vb + ND);
    int* offsets    = counts + N_NODES;
    int* cursor     = offsets + N_NODES;
    int* block_sums = cursor + N_NODES;
    int* csr_cols   = block_sums + 512;

    hipMemsetAsync(counts, 0, (size_t)N_NODES * sizeof(int), stream);

    dim3 g1((N_NODES + 63) / 64, 2, 3);
    qkv_gemm<<<g1, 256, 0, stream>>>(emb, qW, kW, vW, Qb, Kb, Vb);

    hist_kernel<<<(N_EDGES + 255) / 256, 256, 0, stream>>>(rows, counts);
    scan_block<<<NB, 256, 0, stream>>>(counts, offsets, block_sums);
    scan_tops<<<1, 512, 0, stream>>>(block_sums);
    scan_add<<<NB, 256, 0, stream>>>(offsets, block_sums, cursor);
    scatter_kernel<<<(N_EDGES + 255) / 256, 256, 0, stream>>>(rows, cols, cursor, csr_cols);

    fused_node<<<(N_NODES + 3) / 4, 256, 0, stream>>>(
        Qb, Kb, Vb, offsets, counts, csr_cols, emb, gamma, beta, out);
}

// Round 4
// 338.278 us; speedup vs baseline: 3.0144x; 1.2993x over previous
//
#include <hip/hip_runtime.h>
#include <hip/hip_bf16.h>

#define N_NODES 100000
#define N_EDGES 800000
#define D 128
#define NH 8
#define NB ((N_NODES + 255) / 256)   // 391 scan blocks

typedef __hip_bfloat16 bf16;
typedef __bf16 bf16x8 __attribute__((ext_vector_type(8)));
typedef float  f32x4  __attribute__((ext_vector_type(4)));

__device__ __forceinline__ unsigned short f2bu(float x) {
    bf16 b = __float2bfloat16(x);
    return *reinterpret_cast<unsigned short*>(&b);
}
__device__ __forceinline__ float bu2f(unsigned short u) {
    return __uint_as_float(((unsigned)u) << 16);
}
__device__ __forceinline__ float bfe0(unsigned u) { return __uint_as_float(u << 16); }
__device__ __forceinline__ float bfe1(unsigned u) { return __uint_as_float(u & 0xffff0000u); }

union frag_u { unsigned short u[8]; bf16x8 v; };

// ---------------------------------------------------------------------------
// Kernel 0: lay W out in MFMA B-fragment order, split into bf16 hi/lo.
// Element (mat, ct=c*8+t, part, lane, j) at mat*32768 + ct*1024 + part*512
// + lane*8 + j, holding W[k][n] with k=c*32+(lane>>4)*8+j, n=t*16+(lane&15).
// ---------------------------------------------------------------------------
__global__ __launch_bounds__(256) void wf_prep(
    const float* __restrict__ Wq, const float* __restrict__ Wk, const float* __restrict__ Wv,
    unsigned short* __restrict__ Wf)
{
    int t = blockIdx.x * 256 + threadIdx.x;   // over 3*32*64 = 6144
    if (t >= 3 * 32 * 64) return;
    int lane = t & 63;
    int ct   = (t >> 6) & 31;
    int mat  = t >> 11;
    const float* W = (mat == 0) ? Wq : (mat == 1) ? Wk : Wv;
    int c  = ct >> 3, tt = ct & 7;
    int n  = tt * 16 + (lane & 15);
    int kb = c * 32 + (lane >> 4) * 8;
    unsigned short* dst = Wf + (size_t)mat * 32768 + (size_t)ct * 1024 + (size_t)lane * 8;
#pragma unroll
    for (int j = 0; j < 8; ++j) {
        float w  = W[(size_t)(kb + j) * D + n];
        unsigned short hb = f2bu(w);
        float lo = w - bu2f(hb);
        dst[j]       = hb;          // hi (part 0)
        dst[512 + j] = f2bu(lo);    // lo (part 1)
    }
}

// ---------------------------------------------------------------------------
// Kernel 1: fused Q/K/V projection via bf16 MFMA with hi/lo precision split.
// One wave = 16 E-rows; A-frags straight from global; B-frags from Wf.
// Epilogue: C-frags -> LDS (stride 136) -> coalesced bf16 dwordx4 stores.
// ---------------------------------------------------------------------------
__global__ __launch_bounds__(256) void qkv_mfma(
    const float* __restrict__ E, const unsigned short* __restrict__ Wf,
    bf16* __restrict__ Q, bf16* __restrict__ K, bf16* __restrict__ V)
{
    __shared__ unsigned short obuf[4][16 * 136];
    const int wave = threadIdx.x >> 6;
    const int lane = threadIdx.x & 63;
    const int r0 = (blockIdx.x * 4 + wave) * 16;
    if (r0 >= N_NODES) return;

    const int am = lane & 15;    // A row within tile
    const int aq = lane >> 4;    // k quad

    // Load + split this wave's A fragments: 4 k-chunks x 8 bf16.
    const float* erow = E + (size_t)(r0 + am) * D + aq * 8;
    frag_u ahi[4], alo[4];
#pragma unroll
    for (int c = 0; c < 4; ++c) {
        float4 e0 = *reinterpret_cast<const float4*>(erow + c * 32);
        float4 e1 = *reinterpret_cast<const float4*>(erow + c * 32 + 4);
        float ef[8] = {e0.x, e0.y, e0.z, e0.w, e1.x, e1.y, e1.z, e1.w};
#pragma unroll
        for (int j = 0; j < 8; ++j) {
            unsigned short hb = f2bu(ef[j]);
            ahi[c].u[j] = hb;
            alo[c].u[j] = f2bu(ef[j] - bu2f(hb));
        }
    }

    bf16* const Os[3] = {Q, K, V};
    unsigned short* ob = obuf[wave];
    const unsigned short* wfl = Wf + (size_t)lane * 8;

#pragma unroll
    for (int mat = 0; mat < 3; ++mat) {
        f32x4 acc[8];
#pragma unroll
        for (int t = 0; t < 8; ++t) acc[t] = (f32x4){0.f, 0.f, 0.f, 0.f};

        const unsigned short* wfm = wfl + (size_t)mat * 32768;
#pragma unroll
        for (int c = 0; c < 4; ++c) {
#pragma unroll
            for (int t = 0; t < 8; ++t) {
                const unsigned short* bp = wfm + (size_t)(c * 8 + t) * 1024;
                bf16x8 bhi = *reinterpret_cast<const bf16x8*>(bp);
                bf16x8 blo = *reinterpret_cast<const bf16x8*>(bp + 512);
                acc[t] = __builtin_amdgcn_mfma_f32_16x16x32_bf16(alo[c].v, bhi, acc[t], 0, 0, 0);
                acc[t] = __builtin_amdgcn_mfma_f32_16x16x32_bf16(ahi[c].v, blo, acc[t], 0, 0, 0);
                acc[t] = __builtin_amdgcn_mfma_f32_16x16x32_bf16(ahi[c].v, bhi, acc[t], 0, 0, 0);
            }
        }

        // C layout: col = t*16 + (lane&15), row = (lane>>4)*4 + r.
#pragma unroll
        for (int t = 0; t < 8; ++t) {
#pragma unroll
            for (int r = 0; r < 4; ++r)
                ob[(aq * 4 + r) * 136 + t * 16 + am] = f2bu(acc[t][r]);
        }
        // Read back linear: lane -> (row = lane>>2, 32-col chunk = lane&3).
        const int row = lane >> 2, c4 = lane & 3;
        const uint4* src = reinterpret_cast<const uint4*>(ob + row * 136 + c4 * 32);
        uint4 d0 = src[0], d1 = src[1], d2 = src[2], d3 = src[3];
        uint4* dst = reinterpret_cast<uint4*>(Os[mat] + (size_t)(r0 + row) * D + c4 * 32);
        dst[0] = d0; dst[1] = d1; dst[2] = d2; dst[3] = d3;
    }
}

// ---------------------------------------------------------------------------
// CSR build: histogram -> 3-kernel exclusive scan -> scatter  (unchanged)
// ---------------------------------------------------------------------------
__global__ __launch_bounds__(256) void hist_kernel(
    const int* __restrict__ rows, int* __restrict__ counts)
{
    int e = blockIdx.x * 256 + threadIdx.x;
    if (e < N_EDGES) atomicAdd(&counts[rows[e]], 1);
}

__global__ __launch_bounds__(256) void scan_block(
    const int* __restrict__ counts, int* __restrict__ scanned, int* __restrict__ block_sums)
{
    __shared__ int s[256];
    int tid = threadIdx.x;
    int i = blockIdx.x * 256 + tid;
    int v = (i < N_NODES) ? counts[i] : 0;
    s[tid] = v;
    __syncthreads();
#pragma unroll
    for (int off = 1; off < 256; off <<= 1) {
        int t = (tid >= off) ? s[tid - off] : 0;
        __syncthreads();
        s[tid] += t;
        __syncthreads();
    }
    if (i < N_NODES) scanned[i] = s[tid] - v;
    if (tid == 255) block_sums[blockIdx.x] = s[255];
}

__global__ __launch_bounds__(512) void scan_tops(int* __restrict__ block_sums)
{
    __shared__ int s[512];
    int tid = threadIdx.x;
    int v = (tid < NB) ? block_sums[tid] : 0;
    s[tid] = v;
    __syncthreads();
#pragma unroll
    for (int off = 1; off < 512; off <<= 1) {
        int t = (tid >= off) ? s[tid - off] : 0;
        __syncthreads();
        s[tid] += t;
        __syncthreads();
    }
    if (tid < NB) block_sums[tid] = s[tid] - v;
}

__global__ __launch_bounds__(256) void scan_add(
    int* __restrict__ scanned, const int* __restrict__ block_sums, int* __restrict__ cursor)
{
    int i = blockIdx.x * 256 + threadIdx.x;
    if (i < N_NODES) {
        int o = scanned[i] + block_sums[blockIdx.x];
        scanned[i] = o;
        cursor[i]  = o;
    }
}

__global__ __launch_bounds__(256) void scatter_kernel(
    const int* __restrict__ rows, const int* __restrict__ cols,
    int* __restrict__ cursor, int* __restrict__ csr_cols)
{
    int e = blockIdx.x * 256 + threadIdx.x;
    if (e < N_EDGES) {
        int pos = atomicAdd(&cursor[rows[e]], 1);
        csr_cols[pos] = cols[e];
    }
}

// ---------------------------------------------------------------------------
// Fused per-node attention + residual + LayerNorm. One wave per node.
// Edge loop unrolled x2 for load-latency overlap.
// ---------------------------------------------------------------------------
__global__ __launch_bounds__(256) void fused_node(
    const bf16* __restrict__ Qb, const bf16* __restrict__ Kb, const bf16* __restrict__ Vb,
    const int* __restrict__ offsets, const int* __restrict__ counts,
    const int* __restrict__ csr_cols,
    const float* __restrict__ emb,
    const float* __restrict__ gamma, const float* __restrict__ beta,
    float* __restrict__ out)
{
    int n = blockIdx.x * 4 + (threadIdx.x >> 6);
    int lane = threadIdx.x & 63;
    if (n >= N_NODES) return;

    unsigned qu = *reinterpret_cast<const unsigned*>(Qb + (size_t)n * D + lane * 2);
    float q0 = bfe0(qu), q1 = bfe1(qu);

    int start = offsets[n];
    int cnt   = counts[n];

    const bf16* kbase = Kb + lane * 2;
    const bf16* vbase = Vb + lane * 2;

    float acc0 = 0.f, acc1 = 0.f, nrm = 0.f;
    for (int base = 0; base < cnt; base += 64) {
        int m = cnt - base; if (m > 64) m = 64;
        int myc = (base + lane < cnt) ? csr_cols[start + base + lane] : 0;
        int j = 0;
        for (; j + 1 < m; j += 2) {
            int c0 = __shfl(myc, j, 64);
            int c1 = __shfl(myc, j + 1, 64);
            unsigned ku0 = *reinterpret_cast<const unsigned*>(kbase + (size_t)c0 * D);
            unsigned vu0 = *reinterpret_cast<const unsigned*>(vbase + (size_t)c0 * D);
            unsigned ku1 = *reinterpret_cast<const unsigned*>(kbase + (size_t)c1 * D);
            unsigned vu1 = *reinterpret_cast<const unsigned*>(vbase + (size_t)c1 * D);
            float p0 = q0 * bfe0(ku0) + q1 * bfe1(ku0);
            float p1 = q0 * bfe0(ku1) + q1 * bfe1(ku1);
            p0 += __shfl_xor(p0, 1, 64);
            p1 += __shfl_xor(p1, 1, 64);
            p0 += __shfl_xor(p0, 2, 64);
            p1 += __shfl_xor(p1, 2, 64);
            p0 += __shfl_xor(p0, 4, 64);
            p1 += __shfl_xor(p1, 4, 64);
            float s0 = __expf(fminf(fmaxf(p0, -10.f), 10.f));
            float s1 = __expf(fminf(fmaxf(p1, -10.f), 10.f));
            nrm  += s0 + s1;
            acc0 += s0 * bfe0(vu0) + s1 * bfe0(vu1);
            acc1 += s0 * bfe1(vu0) + s1 * bfe1(vu1);
        }
        if (j < m) {
            int c0 = __shfl(myc, j, 64);
            unsigned ku0 = *reinterpret_cast<const unsigned*>(kbase + (size_t)c0 * D);
            unsigned vu0 = *reinterpret_cast<const unsigned*>(vbase + (size_t)c0 * D);
            float p0 = q0 * bfe0(ku0) + q1 * bfe1(ku0);
            p0 += __shfl_xor(p0, 1, 64);
            p0 += __shfl_xor(p0, 2, 64);
            p0 += __shfl_xor(p0, 4, 64);
            float s0 = __expf(fminf(fmaxf(p0, -10.f), 10.f));
            nrm  += s0;
            acc0 += s0 * bfe0(vu0);
            acc1 += s0 * bfe1(vu0);
        }
    }

    float w = 1.f / (nrm + 1e-8f);
    float2 e2 = *reinterpret_cast<const float2*>(emb + (size_t)n * D + lane * 2);
    float x0 = acc0 * w + e2.x;
    float x1 = acc1 * w + e2.y;

    float ssum = x0 + x1;
#pragma unroll
    for (int off = 32; off; off >>= 1) ssum += __shfl_xor(ssum, off, 64);
    float mean = ssum * (1.0f / 128.0f);
    float d0 = x0 - mean, d1 = x1 - mean;
    float var = d0 * d0 + d1 * d1;
#pragma unroll
    for (int off = 32; off; off >>= 1) var += __shfl_xor(var, off, 64);
    float rs = rsqrtf(var * (1.0f / 128.0f) + 1e-6f);

    float2 g2 = *reinterpret_cast<const float2*>(gamma + lane * 2);
    float2 b2 = *reinterpret_cast<const float2*>(beta + lane * 2);
    float2 o2 = make_float2(d0 * rs * g2.x + b2.x, d1 * rs * g2.y + b2.y);
    *reinterpret_cast<float2*>(out + (size_t)n * D + lane * 2) = o2;
}

// ---------------------------------------------------------------------------
extern "C" void kernel_launch(void* const* d_in, const int* in_sizes, int n_in,
                              void* d_out, int out_size, void* d_ws, size_t ws_size,
                              hipStream_t stream)
{
    const float* emb   = (const float*)d_in[0];
    const float* qW    = (const float*)d_in[1];
    const float* kW    = (const float*)d_in[2];
    const float* vW    = (const float*)d_in[3];
    const float* gamma = (const float*)d_in[4];
    const float* beta  = (const float*)d_in[5];
    const int*   eidx  = (const int*)d_in[6];
    const int*   rows  = eidx;
    const int*   cols  = eidx + N_EDGES;
    float* out = (float*)d_out;

    const size_t ND = (size_t)N_NODES * D;
    bf16* Qb = (bf16*)d_ws;
    bf16* Kb = Qb + ND;
    bf16* Vb = Kb + ND;
    int* counts     = (int*)(Vb + ND);
    int* offsets    = counts + N_NODES;
    int* cursor     = offsets + N_NODES;
    int* block_sums = cursor + N_NODES;
    int* csr_cols   = block_sums + 512;
    unsigned short* Wf = (unsigned short*)(csr_cols + N_EDGES);  // 3*32768 ushort

    hipMemsetAsync(counts, 0, (size_t)N_NODES * sizeof(int), stream);

    wf_prep<<<24, 256, 0, stream>>>(qW, kW, vW, Wf);
    qkv_mfma<<<(N_NODES + 63) / 64, 256, 0, stream>>>(emb, Wf, Qb, Kb, Vb);

    hist_kernel<<<(N_EDGES + 255) / 256, 256, 0, stream>>>(rows, counts);
    scan_block<<<NB, 256, 0, stream>>>(counts, offsets, block_sums);
    scan_tops<<<1, 512, 0, stream>>>(block_sums);
    scan_add<<<NB, 256, 0, stream>>>(offsets, block_sums, cursor);
    scatter_kernel<<<(N_EDGES + 255) / 256, 256, 0, stream>>>(rows, cols, cursor, csr_cols);

    fused_node<<<(N_NODES + 3) / 4, 256, 0, stream>>>(
        Qb, Kb, Vb, offsets, counts, csr_cols, emb, gamma, beta, out);
}

// Round 5
// 315.315 us; speedup vs baseline: 3.2339x; 1.0728x over previous
//
#include <hip/hip_runtime.h>
#include <hip/hip_bf16.h>

#define N_NODES 100000
#define N_EDGES 800000
#define D 128
#define NH 8
#define NB ((N_NODES + 255) / 256)   // 391 scan blocks

typedef __hip_bfloat16 bf16;
typedef __bf16 bf16x8 __attribute__((ext_vector_type(8)));
typedef float  f32x4  __attribute__((ext_vector_type(4)));

__device__ __forceinline__ unsigned short f2bu(float x) {
    bf16 b = __float2bfloat16(x);
    return *reinterpret_cast<unsigned short*>(&b);
}
__device__ __forceinline__ float bu2f(unsigned short u) {
    return __uint_as_float(((unsigned)u) << 16);
}
__device__ __forceinline__ float bfe0(unsigned u) { return __uint_as_float(u << 16); }
__device__ __forceinline__ float bfe1(unsigned u) { return __uint_as_float(u & 0xffff0000u); }

union frag_u { unsigned short u[8]; bf16x8 v; };

// ---------------------------------------------------------------------------
// Kernel 0: lay W out in MFMA B-fragment order, split into bf16 hi/lo.
// Element (mat, ct=c*8+t, part, lane, j) at mat*32768 + ct*1024 + part*512
// + lane*8 + j, holding W[k][n] with k=c*32+(lane>>4)*8+j, n=t*16+(lane&15).
// ---------------------------------------------------------------------------
__global__ __launch_bounds__(256) void wf_prep(
    const float* __restrict__ Wq, const float* __restrict__ Wk, const float* __restrict__ Wv,
    unsigned short* __restrict__ Wf)
{
    int t = blockIdx.x * 256 + threadIdx.x;   // over 3*32*64 = 6144
    if (t >= 3 * 32 * 64) return;
    int lane = t & 63;
    int ct   = (t >> 6) & 31;
    int mat  = t >> 11;
    const float* W = (mat == 0) ? Wq : (mat == 1) ? Wk : Wv;
    int c  = ct >> 3, tt = ct & 7;
    int n  = tt * 16 + (lane & 15);
    int kb = c * 32 + (lane >> 4) * 8;
    unsigned short* dst = Wf + (size_t)mat * 32768 + (size_t)ct * 1024 + (size_t)lane * 8;
#pragma unroll
    for (int j = 0; j < 8; ++j) {
        float w  = W[(size_t)(kb + j) * D + n];
        unsigned short hb = f2bu(w);
        float lo = w - bu2f(hb);
        dst[j]       = hb;          // hi (part 0)
        dst[512 + j] = f2bu(lo);    // lo (part 1)
    }
}

// ---------------------------------------------------------------------------
// Kernel 1: fused Q/K/V projection via bf16 MFMA with hi/lo precision split.
// Block = 4 waves x 32 rows = 128 rows.  B-frags staged block-wide in LDS
// (32 KB halves); the same LDS buffer is reused as the per-wave epilogue
// transpose buffer.  A-frags straight from global.
// ---------------------------------------------------------------------------
__global__ __launch_bounds__(256) void qkv_mfma(
    const float* __restrict__ E, const unsigned short* __restrict__ Wf,
    bf16* __restrict__ Q, bf16* __restrict__ K, bf16* __restrict__ V)
{
    __shared__ unsigned short bsh[16384];   // 32 KB: B staging, then epilogue
    const int tid  = threadIdx.x;
    const int wave = tid >> 6;
    const int lane = tid & 63;
    const int r0w  = blockIdx.x * 128 + wave * 32;   // this wave's 32 rows

    const int am = lane & 15;    // A row within 16-tile
    const int aq = lane >> 4;    // k quad

    // Load + split A fragments: 2 row-tiles x 4 k-chunks x 8 bf16 (hi/lo).
    frag_u ahi[2][4], alo[2][4];
#pragma unroll
    for (int rt = 0; rt < 2; ++rt) {
        int row = r0w + rt * 16 + am;
        if (row >= N_NODES) row = N_NODES - 1;     // clamp; stores are guarded
        const float* erow = E + (size_t)row * D + aq * 8;
#pragma unroll
        for (int c = 0; c < 4; ++c) {
            float4 e0 = *reinterpret_cast<const float4*>(erow + c * 32);
            float4 e1 = *reinterpret_cast<const float4*>(erow + c * 32 + 4);
            float ef[8] = {e0.x, e0.y, e0.z, e0.w, e1.x, e1.y, e1.z, e1.w};
#pragma unroll
            for (int j = 0; j < 8; ++j) {
                unsigned short hb = f2bu(ef[j]);
                ahi[rt][c].u[j] = hb;
                alo[rt][c].u[j] = f2bu(ef[j] - bu2f(hb));
            }
        }
    }

    bf16* const Os[3] = {Q, K, V};

#pragma unroll
    for (int mat = 0; mat < 3; ++mat) {
        f32x4 acc[8][2];
#pragma unroll
        for (int t = 0; t < 8; ++t)
#pragma unroll
            for (int rt = 0; rt < 2; ++rt)
                acc[t][rt] = (f32x4){0.f, 0.f, 0.f, 0.f};

        const unsigned short* wm = Wf + (size_t)mat * 32768;

#pragma unroll
        for (int half = 0; half < 2; ++half) {
            __syncthreads();    // previous users of bsh are done
            // Stage 32 KB (c = 2*half .. 2*half+1): 2048 uint4, 8 per thread.
            const uint4* src = reinterpret_cast<const uint4*>(wm + half * 16384);
            uint4* dstv = reinterpret_cast<uint4*>(bsh);
#pragma unroll
            for (int k = 0; k < 8; ++k)
                dstv[k * 256 + tid] = src[k * 256 + tid];
            __syncthreads();

#pragma unroll
            for (int t = 0; t < 8; ++t) {
#pragma unroll
                for (int cc = 0; cc < 2; ++cc) {
                    const unsigned short* bp = bsh + (cc * 8 + t) * 1024 + lane * 8;
                    bf16x8 bhi = *reinterpret_cast<const bf16x8*>(bp);
                    bf16x8 blo = *reinterpret_cast<const bf16x8*>(bp + 512);
                    const int c = half * 2 + cc;
#pragma unroll
                    for (int rt = 0; rt < 2; ++rt) {
                        acc[t][rt] = __builtin_amdgcn_mfma_f32_16x16x32_bf16(alo[rt][c].v, bhi, acc[t][rt], 0, 0, 0);
                        acc[t][rt] = __builtin_amdgcn_mfma_f32_16x16x32_bf16(ahi[rt][c].v, blo, acc[t][rt], 0, 0, 0);
                        acc[t][rt] = __builtin_amdgcn_mfma_f32_16x16x32_bf16(ahi[rt][c].v, bhi, acc[t][rt], 0, 0, 0);
                    }
                }
            }
        }
        __syncthreads();   // all waves done reading B; bsh reusable per-wave

        // Epilogue: C-frags -> per-wave LDS slice (stride 136) -> coalesced
        // dwordx4 bf16 stores.  C layout: col = t*16+am, row = aq*4+r.
        unsigned short* ob = bsh + wave * 2176;   // 16 rows x 136
#pragma unroll
        for (int rt = 0; rt < 2; ++rt) {
#pragma unroll
            for (int t = 0; t < 8; ++t)
#pragma unroll
                for (int r = 0; r < 4; ++r)
                    ob[(aq * 4 + r) * 136 + t * 16 + am] = f2bu(acc[t][rt][r]);
            const int row = lane >> 2, c4 = lane & 3;
            int grow = r0w + rt * 16 + row;
            if (grow < N_NODES) {
                const uint4* srcb = reinterpret_cast<const uint4*>(ob + row * 136 + c4 * 32);
                uint4 d0 = srcb[0], d1 = srcb[1], d2 = srcb[2], d3 = srcb[3];
                uint4* dst = reinterpret_cast<uint4*>(Os[mat] + (size_t)grow * D + c4 * 32);
                dst[0] = d0; dst[1] = d1; dst[2] = d2; dst[3] = d3;
            }
        }
    }
}

// ---------------------------------------------------------------------------
// CSR build: histogram -> 3-kernel exclusive scan -> scatter  (unchanged)
// ---------------------------------------------------------------------------
__global__ __launch_bounds__(256) void hist_kernel(
    const int* __restrict__ rows, int* __restrict__ counts)
{
    int e = blockIdx.x * 256 + threadIdx.x;
    if (e < N_EDGES) atomicAdd(&counts[rows[e]], 1);
}

__global__ __launch_bounds__(256) void scan_block(
    const int* __restrict__ counts, int* __restrict__ scanned, int* __restrict__ block_sums)
{
    __shared__ int s[256];
    int tid = threadIdx.x;
    int i = blockIdx.x * 256 + tid;
    int v = (i < N_NODES) ? counts[i] : 0;
    s[tid] = v;
    __syncthreads();
#pragma unroll
    for (int off = 1; off < 256; off <<= 1) {
        int t = (tid >= off) ? s[tid - off] : 0;
        __syncthreads();
        s[tid] += t;
        __syncthreads();
    }
    if (i < N_NODES) scanned[i] = s[tid] - v;
    if (tid == 255) block_sums[blockIdx.x] = s[255];
}

__global__ __launch_bounds__(512) void scan_tops(int* __restrict__ block_sums)
{
    __shared__ int s[512];
    int tid = threadIdx.x;
    int v = (tid < NB) ? block_sums[tid] : 0;
    s[tid] = v;
    __syncthreads();
#pragma unroll
    for (int off = 1; off < 512; off <<= 1) {
        int t = (tid >= off) ? s[tid - off] : 0;
        __syncthreads();
        s[tid] += t;
        __syncthreads();
    }
    if (tid < NB) block_sums[tid] = s[tid] - v;
}

__global__ __launch_bounds__(256) void scan_add(
    int* __restrict__ scanned, const int* __restrict__ block_sums, int* __restrict__ cursor)
{
    int i = blockIdx.x * 256 + threadIdx.x;
    if (i < N_NODES) {
        int o = scanned[i] + block_sums[blockIdx.x];
        scanned[i] = o;
        cursor[i]  = o;
    }
}

__global__ __launch_bounds__(256) void scatter_kernel(
    const int* __restrict__ rows, const int* __restrict__ cols,
    int* __restrict__ cursor, int* __restrict__ csr_cols)
{
    int e = blockIdx.x * 256 + threadIdx.x;
    if (e < N_EDGES) {
        int pos = atomicAdd(&cursor[rows[e]], 1);
        csr_cols[pos] = cols[e];
    }
}

// ---------------------------------------------------------------------------
// Fused per-node attention + residual + LayerNorm. One wave per node.
// Edge loop unrolled x2 for load-latency overlap.  (unchanged this round)
// ---------------------------------------------------------------------------
__global__ __launch_bounds__(256) void fused_node(
    const bf16* __restrict__ Qb, const bf16* __restrict__ Kb, const bf16* __restrict__ Vb,
    const int* __restrict__ offsets, const int* __restrict__ counts,
    const int* __restrict__ csr_cols,
    const float* __restrict__ emb,
    const float* __restrict__ gamma, const float* __restrict__ beta,
    float* __restrict__ out)
{
    int n = blockIdx.x * 4 + (threadIdx.x >> 6);
    int lane = threadIdx.x & 63;
    if (n >= N_NODES) return;

    unsigned qu = *reinterpret_cast<const unsigned*>(Qb + (size_t)n * D + lane * 2);
    float q0 = bfe0(qu), q1 = bfe1(qu);

    int start = offsets[n];
    int cnt   = counts[n];

    const bf16* kbase = Kb + lane * 2;
    const bf16* vbase = Vb + lane * 2;

    float acc0 = 0.f, acc1 = 0.f, nrm = 0.f;
    for (int base = 0; base < cnt; base += 64) {
        int m = cnt - base; if (m > 64) m = 64;
        int myc = (base + lane < cnt) ? csr_cols[start + base + lane] : 0;
        int j = 0;
        for (; j + 1 < m; j += 2) {
            int c0 = __shfl(myc, j, 64);
            int c1 = __shfl(myc, j + 1, 64);
            unsigned ku0 = *reinterpret_cast<const unsigned*>(kbase + (size_t)c0 * D);
            unsigned vu0 = *reinterpret_cast<const unsigned*>(vbase + (size_t)c0 * D);
            unsigned ku1 = *reinterpret_cast<const unsigned*>(kbase + (size_t)c1 * D);
            unsigned vu1 = *reinterpret_cast<const unsigned*>(vbase + (size_t)c1 * D);
            float p0 = q0 * bfe0(ku0) + q1 * bfe1(ku0);
            float p1 = q0 * bfe0(ku1) + q1 * bfe1(ku1);
            p0 += __shfl_xor(p0, 1, 64);
            p1 += __shfl_xor(p1, 1, 64);
            p0 += __shfl_xor(p0, 2, 64);
            p1 += __shfl_xor(p1, 2, 64);
            p0 += __shfl_xor(p0, 4, 64);
            p1 += __shfl_xor(p1, 4, 64);
            float s0 = __expf(fminf(fmaxf(p0, -10.f), 10.f));
            float s1 = __expf(fminf(fmaxf(p1, -10.f), 10.f));
            nrm  += s0 + s1;
            acc0 += s0 * bfe0(vu0) + s1 * bfe0(vu1);
            acc1 += s0 * bfe1(vu0) + s1 * bfe1(vu1);
        }
        if (j < m) {
            int c0 = __shfl(myc, j, 64);
            unsigned ku0 = *reinterpret_cast<const unsigned*>(kbase + (size_t)c0 * D);
            unsigned vu0 = *reinterpret_cast<const unsigned*>(vbase + (size_t)c0 * D);
            float p0 = q0 * bfe0(ku0) + q1 * bfe1(ku0);
            p0 += __shfl_xor(p0, 1, 64);
            p0 += __shfl_xor(p0, 2, 64);
            p0 += __shfl_xor(p0, 4, 64);
            float s0 = __expf(fminf(fmaxf(p0, -10.f), 10.f));
            nrm  += s0;
            acc0 += s0 * bfe0(vu0);
            acc1 += s0 * bfe1(vu0);
        }
    }

    float w = 1.f / (nrm + 1e-8f);
    float2 e2 = *reinterpret_cast<const float2*>(emb + (size_t)n * D + lane * 2);
    float x0 = acc0 * w + e2.x;
    float x1 = acc1 * w + e2.y;

    float ssum = x0 + x1;
#pragma unroll
    for (int off = 32; off; off >>= 1) ssum += __shfl_xor(ssum, off, 64);
    float mean = ssum * (1.0f / 128.0f);
    float d0 = x0 - mean, d1 = x1 - mean;
    float var = d0 * d0 + d1 * d1;
#pragma unroll
    for (int off = 32; off; off >>= 1) var += __shfl_xor(var, off, 64);
    float rs = rsqrtf(var * (1.0f / 128.0f) + 1e-6f);

    float2 g2 = *reinterpret_cast<const float2*>(gamma + lane * 2);
    float2 b2 = *reinterpret_cast<const float2*>(beta + lane * 2);
    float2 o2 = make_float2(d0 * rs * g2.x + b2.x, d1 * rs * g2.y + b2.y);
    *reinterpret_cast<float2*>(out + (size_t)n * D + lane * 2) = o2;
}

// ---------------------------------------------------------------------------
extern "C" void kernel_launch(void* const* d_in, const int* in_sizes, int n_in,
                              void* d_out, int out_size, void* d_ws, size_t ws_size,
                              hipStream_t stream)
{
    const float* emb   = (const float*)d_in[0];
    const float* qW    = (const float*)d_in[1];
    const float* kW    = (const float*)d_in[2];
    const float* vW    = (const float*)d_in[3];
    const float* gamma = (const float*)d_in[4];
    const float* beta  = (const float*)d_in[5];
    const int*   eidx  = (const int*)d_in[6];
    const int*   rows  = eidx;
    const int*   cols  = eidx + N_EDGES;
    float* out = (float*)d_out;

    const size_t ND = (size_t)N_NODES * D;
    bf16* Qb = (bf16*)d_ws;
    bf16* Kb = Qb + ND;
    bf16* Vb = Kb + ND;
    int* counts     = (int*)(Vb + ND);
    int* offsets    = counts + N_NODES;
    int* cursor     = offsets + N_NODES;
    int* block_sums = cursor + N_NODES;
    int* csr_cols   = block_sums + 512;
    unsigned short* Wf = (unsigned short*)(csr_cols + N_EDGES);  // 3*32768 ushort

    hipMemsetAsync(counts, 0, (size_t)N_NODES * sizeof(int), stream);

    wf_prep<<<24, 256, 0, stream>>>(qW, kW, vW, Wf);
    qkv_mfma<<<(N_NODES + 127) / 128, 256, 0, stream>>>(emb, Wf, Qb, Kb, Vb);

    hist_kernel<<<(N_EDGES + 255) / 256, 256, 0, stream>>>(rows, counts);
    scan_block<<<NB, 256, 0, stream>>>(counts, offsets, block_sums);
    scan_tops<<<1, 512, 0, stream>>>(block_sums);
    scan_add<<<NB, 256, 0, stream>>>(offsets, block_sums, cursor);
    scatter_kernel<<<(N_EDGES + 255) / 256, 256, 0, stream>>>(rows, cols, cursor, csr_cols);

    fused_node<<<(N_NODES + 3) / 4, 256, 0, stream>>>(
        Qb, Kb, Vb, offsets, counts, csr_cols, emb, gamma, beta, out);
}